// Round 11
// baseline (7936.475 us; speedup 1.0000x reference)
//
#include <hip/hip_runtime.h>

#define SS 512
#define NWG 100
#define NTHR 512
#define OUT_HID_OFF 8388608   // 32*512*512

typedef _Float16 fh8 __attribute__((ext_vector_type(8)));
typedef float f32x4 __attribute__((ext_vector_type(4)));

struct GP {
  const float *x;
  const float *Wxz0,*bxz0,*Whz0,*Wxr0,*bxr0,*Whr0,*Wxg0,*bxg0,*Whg0;
  const float *Wxz1,*bxz1,*Whz1,*Wxr1,*bxr1,*Whr1,*Wxg1,*bxg1,*Whg1;
  const float *Why,*bhy;
  float *out;
  _Float16 *xb;                       // [32][512][512] f16
  _Float16 *wzr0,*wzr1,*wg0,*wg1,*wy; // packed B-fragment order
  float *h0f,*h1f;                    // [4][32][1024] f32 rings
  _Float16 *h0h,*h1h;                 // [4][32][1024] f16 rings
  float *z0,*z1;                      // [2][32][1024] f32 rings
  _Float16 *r0,*r1;                   // [2][32][1024] f16 rings
  unsigned *fg0,*fg1;                 // 16 flags each (stride 32 u32)
  unsigned *fzr0,*fzr1;               // 32 flags each
  unsigned *fy;                       // 4 flags
};

// ---------- accessors (r10-proven) ----------
__device__ __forceinline__ void astoref(float* p, float v) {
  __hip_atomic_store(p, v, __ATOMIC_RELAXED, __HIP_MEMORY_SCOPE_AGENT);
}
__device__ __forceinline__ void astore2f(float* p, float a, float b) {
  unsigned long long u;
  float t[2] = {a, b};
  __builtin_memcpy(&u, t, 8);
  __hip_atomic_store((unsigned long long*)p, u, __ATOMIC_RELAXED, __HIP_MEMORY_SCOPE_AGENT);
}
__device__ __forceinline__ void astoreu(unsigned* p, unsigned v) {
  __hip_atomic_store(p, v, __ATOMIC_RELAXED, __HIP_MEMORY_SCOPE_AGENT);
}
__device__ __forceinline__ void bload(uint4& d, const void* p) {
  asm volatile("global_load_dwordx4 %0, %1, off sc0 sc1"
               : "=&v"(d) : "v"(p) : "memory");
}
__device__ __forceinline__ void bload1(float& d, const float* p) {
  asm volatile("global_load_dword %0, %1, off sc0 sc1"
               : "=&v"(d) : "v"(p) : "memory");
}
__device__ __forceinline__ fh8 u2h(uint4 v){ fh8 r; __builtin_memcpy(&r, &v, 16); return r; }
__device__ __forceinline__ uint4 h2u(fh8 v){ uint4 r; __builtin_memcpy(&r, &v, 16); return r; }
__device__ __forceinline__ float sigmf(float v){ return 1.f/(1.f+__expf(-v)); }
// pack (own, lane^1) f16 pair; stored by even lanes
__device__ __forceinline__ unsigned pkpair(float v) {
  float o = __shfl_xor(v, 1, 64);
  _Float16 ha = (_Float16)v, hb = (_Float16)o;
  unsigned short ua, ub;
  __builtin_memcpy(&ua,&ha,2); __builtin_memcpy(&ub,&hb,2);
  return (unsigned)ua | ((unsigned)ub << 16);
}

// ---------- one-time pack (r10 verbatim) ----------
__global__ __launch_bounds__(256) void pack(GP p) {
  const long gid = (long)blockIdx.x*256 + threadIdx.x;
  if (gid < 1441792) {
    long u; int KC; _Float16* dst;
    if (gid < 393216)       { u=gid;         KC=48; dst=p.wzr0; }
    else if (gid < 917504)  { u=gid-393216;  KC=64; dst=p.wzr1; }
    else if (gid < 1114112) { u=gid-917504;  KC=48; dst=p.wg0;  }
    else if (gid < 1376256) { u=gid-1114112; KC=64; dst=p.wg1;  }
    else                    { u=gid-1376256; KC=32; dst=p.wy;   }
    const int per = KC*64;
    const int ntg = (int)(u/per); const int r = (int)(u%per);
    const int kc = r>>6, lane = r&63;
    const int n = ntg*16 + (lane&15);
    const int k = kc*32 + ((lane>>4)<<3);
    const float* src;
    if (gid < 393216) {
      int g = n>>10, nn = n&1023;
      src = (k<512) ? ((g?p.Wxr0:p.Wxz0) + (size_t)nn*512 + k)
                    : ((g?p.Whr0:p.Whz0) + (size_t)nn*1024 + (k-512));
    } else if (gid < 917504) {
      int g = n>>10, nn = n&1023;
      src = (k<1024) ? ((g?p.Wxr1:p.Wxz1) + (size_t)nn*1024 + k)
                     : ((g?p.Whr1:p.Whz1) + (size_t)nn*1024 + (k-1024));
    } else if (gid < 1114112) {
      src = (k<512) ? (p.Wxg0 + (size_t)n*512 + k)
                    : (p.Whg0 + (size_t)n*1024 + (k-512));
    } else if (gid < 1376256) {
      src = (k<1024) ? (p.Wxg1 + (size_t)n*1024 + k)
                     : (p.Whg1 + (size_t)n*1024 + (k-1024));
    } else {
      src = p.Why + (size_t)n*1024 + k;
    }
    float4 f0 = *(const float4*)src, f1 = *(const float4*)(src+4);
    fh8 h;
    h[0]=(_Float16)f0.x; h[1]=(_Float16)f0.y; h[2]=(_Float16)f0.z; h[3]=(_Float16)f0.w;
    h[4]=(_Float16)f1.x; h[5]=(_Float16)f1.y; h[6]=(_Float16)f1.z; h[7]=(_Float16)f1.w;
    *(fh8*)(dst + u*8) = h;
  } else if (gid < 2490368) {
    const long e = (gid - 1441792)*8;
    float4 f0 = *(const float4*)(p.x + e), f1 = *(const float4*)(p.x + e + 4);
    fh8 h;
    h[0]=(_Float16)f0.x; h[1]=(_Float16)f0.y; h[2]=(_Float16)f0.z; h[3]=(_Float16)f0.w;
    h[4]=(_Float16)f1.x; h[5]=(_Float16)f1.y; h[6]=(_Float16)f1.z; h[7]=(_Float16)f1.w;
    *(fh8*)(p.xb + e) = h;
  }
}

// ---------- dataflow sync ----------
__device__ __forceinline__ void pollone(const unsigned* f, int need) {
  if (f && need > 0)
    while ((int)__hip_atomic_load(f, __ATOMIC_RELAXED, __HIP_MEMORY_SCOPE_AGENT) < need)
      __builtin_amdgcn_s_sleep(1);
}
__device__ __forceinline__ void waitf(const unsigned* fb, int n, int need) {
  if (need > 0) {
    if ((int)threadIdx.x < n)
      pollone(fb + (size_t)threadIdx.x*32, need);
    asm volatile("" ::: "memory");
    __syncthreads();
  }
}
__device__ __forceinline__ void setflag(unsigned* f, unsigned v) {
  asm volatile("s_waitcnt vmcnt(0) lgkmcnt(0)" ::: "memory");
  __syncthreads();
  if (threadIdx.x == 0)
    __hip_atomic_store(f, v, __ATOMIC_RELAXED, __HIP_MEMORY_SCOPE_AGENT);
}

// ---------- staging helpers (r10 verbatim) ----------
__device__ __forceinline__ void issue_copy(uint4* R, const _Float16* base, int row, int s16) {
  const char* sp = (const char*)(base + (size_t)row*1024) + s16*64;
  bload(R[0], sp); bload(R[1], sp+16); bload(R[2], sp+32); bload(R[3], sp+48);
}
__device__ __forceinline__ void issue_prod(uint4* Ra, uint4* Rh,
    const _Float16* ra, const _Float16* ha, int row, int s16) {
  const char* rp = (const char*)(ra + (size_t)row*1024) + s16*64;
  const char* hp = (const char*)(ha + (size_t)row*1024) + s16*64;
  #pragma unroll
  for (int q = 0; q < 4; ++q) { bload(Ra[q], rp + q*16); bload(Rh[q], hp + q*16); }
}
__device__ __forceinline__ void issue_x(uint4* R, const _Float16* xab, int row, int s16) {
  const uint4* sp = (const uint4*)(xab + (size_t)row*262144 + (size_t)s16*32);
  R[0]=sp[0]; R[1]=sp[1]; R[2]=sp[2]; R[3]=sp[3];
}
__device__ __forceinline__ void commit4(const uint4* R, char* As, int s, int row, int s16) {
  const int key = (row & 15) << 4;
  char* d = As + (size_t)row*4096;
  const int kb0 = s*1024 + s16*64;
  #pragma unroll
  for (int q = 0; q < 4; ++q) *(uint4*)(d + ((kb0 + q*16) ^ key)) = R[q];
}
__device__ __forceinline__ void commit_prod(const uint4* Ra, const uint4* Rh,
    char* As, int s, int row, int s16) {
  const int key = (row & 15) << 4;
  char* d = As + (size_t)row*4096;
  const int kb0 = s*1024 + s16*64;
  #pragma unroll
  for (int q = 0; q < 4; ++q) {
    fh8 o = u2h(Ra[q]) * u2h(Rh[q]);
    *(uint4*)(d + ((kb0 + q*16) ^ key)) = h2u(o);
  }
}

// ---------- MFMA sweeps ----------
// half-row sweep: one acc, rows half*16..half*16+15
__device__ __forceinline__ void sweep_half(const char* As, const _Float16* wpk,
    int ntg, int KC, int k0, int k1, int l, int half, f32x4& acc) {
  const int lrow = l & 15, key = lrow << 4, lg16 = (l >> 4) << 4;
  const char* ab = As + (size_t)lrow*4096 + (size_t)half*16*4096;
  const _Float16* wb = wpk + (size_t)ntg*KC*512 + (size_t)l*8;
  #pragma unroll 8
  for (int kk = k0; kk < k1; ++kk) {
    const int off = (kk*64 + lg16) ^ key;
    fh8 a = *(const fh8*)(ab + off);
    fh8 b = *(const fh8*)(wb + (size_t)kk*512);
    acc = __builtin_amdgcn_mfma_f32_16x16x32_f16(a, b, acc, 0, 0, 0);
  }
}
// full sweep (Y group, r10 verbatim)
__device__ __forceinline__ void sweep_range(const char* As, const _Float16* wpk,
    int ntg, int KC, int k0, int k1, int l, f32x4& acc0, f32x4& acc1) {
  const int lrow = l & 15, key = lrow << 4, lg16 = (l >> 4) << 4;
  const char* ab = As + (size_t)lrow*4096;
  const _Float16* wb = wpk + (size_t)ntg*KC*512 + (size_t)l*8;
  #pragma unroll 8
  for (int kk = k0; kk < k1; ++kk) {
    const int off = (kk*64 + lg16) ^ key;
    fh8 a0 = *(const fh8*)(ab + off);
    fh8 a1 = *(const fh8*)(ab + 16*4096 + off);
    fh8 b  = *(const fh8*)(wb + (size_t)kk*512);
    acc0 = __builtin_amdgcn_mfma_f32_16x16x32_f16(a0, b, acc0, 0, 0, 0);
    acc1 = __builtin_amdgcn_mfma_f32_16x16x32_f16(a1, b, acc1, 0, 0, 0);
  }
}

// ---------- packed epilogues (col = tile*16 + (l&15); row = half*16 + (l>>4)*4 + q) ----------
__device__ __forceinline__ void epi_zr_p(const f32x4& a, int tile, int half, int l,
    const float* bz, const float* br, float* zbuf, _Float16* rbuf) {
  const int col = (tile << 4) | (l & 15);
  const int gate = col >> 10, cc = col & 1023;
  const float bias = gate ? br[cc] : bz[cc];
  const int r0 = half*16 + ((l >> 4) << 2);
  #pragma unroll
  for (int q = 0; q < 4; ++q) {
    const float v = sigmf(a[q] + bias);
    if (gate) {
      unsigned w = pkpair(v);
      if (!(l & 1)) astoreu((unsigned*)(rbuf + (size_t)(r0+q)*1024 + cc), w);
    } else {
      float o = __shfl_xor(v, 1, 64);
      if (!(l & 1)) astore2f(zbuf + (size_t)(r0+q)*1024 + cc, v, o);
    }
  }
}

// ---------- main persistent kernel: dataflow + merged waits + half-split ----------
__global__ __launch_bounds__(NTHR, 2) void gru_main(GP p) {
  __shared__ char As[131072];
  const int tid = threadIdx.x, wg = blockIdx.x;
  const int wid = tid >> 6, l = tid & 63;
  const int row = tid >> 4, s16 = tid & 15;
  const int half = wid >> 2;

  if (wg < 32) {
    // ================= ZR0: z0,r0(t) — 32 WGs, tile=wg*4+(wid&3) =================
    const int tile = wg*4 + (wid & 3);
    for (int t = 0; t < SS; ++t) {
      { uint4 Rx[4];
        issue_x(Rx, p.xb + (size_t)t*512, row, s16);
        commit4(Rx, As, 0, row, s16); }
      __syncthreads();
      f32x4 a = {0.f,0.f,0.f,0.f};
      sweep_half(As, p.wzr0, tile, 48, 0, 16, l, half, a);
      waitf(p.fg0, 16, t);                       // h0(t-1)
      { const _Float16* hb = p.h0h + (size_t)((t-1)&3)*32768;
        uint4 R0[4], R1[4];
        issue_copy(R0, hb, row, s16);
        issue_copy(R1, hb+512, row, s16);
        asm volatile("s_waitcnt vmcnt(0)" ::: "memory");
        __builtin_amdgcn_sched_barrier(0);
        commit4(R0, As, 1, row, s16);
        commit4(R1, As, 2, row, s16); }
      __syncthreads();
      sweep_half(As, p.wzr0, tile, 48, 16, 48, l, half, a);
      epi_zr_p(a, tile, half, l, p.bxz0, p.bxr0,
               p.z0 + (size_t)(t&1)*32768, p.r0 + (size_t)(t&1)*32768);
      setflag(p.fzr0 + (size_t)wg*32, (unsigned)(t+1));
    }
  } else if (wg < 64) {
    // ================= ZR1: z1,r1(t) — 32 WGs =================
    const int tile = (wg-32)*4 + (wid & 3);
    for (int t = 0; t < SS; ++t) {
      waitf(p.fg0, 16, t+1);                     // h0(t)
      { const _Float16* hb = p.h0h + (size_t)(t&3)*32768;
        uint4 R0[4], R1[4];
        issue_copy(R0, hb, row, s16);
        issue_copy(R1, hb+512, row, s16);
        asm volatile("s_waitcnt vmcnt(0)" ::: "memory");
        __builtin_amdgcn_sched_barrier(0);
        commit4(R0, As, 0, row, s16);
        commit4(R1, As, 1, row, s16); }
      __syncthreads();
      f32x4 a = {0.f,0.f,0.f,0.f};
      sweep_half(As, p.wzr1, tile, 64, 0, 32, l, half, a);
      waitf(p.fg1, 16, t);                       // h1(t-1)
      { const _Float16* hb = p.h1h + (size_t)((t-1)&3)*32768;
        uint4 R0[4], R1[4];
        issue_copy(R0, hb, row, s16);
        issue_copy(R1, hb+512, row, s16);
        asm volatile("s_waitcnt vmcnt(0)" ::: "memory");
        __builtin_amdgcn_sched_barrier(0);
        commit4(R0, As, 2, row, s16);
        commit4(R1, As, 3, row, s16); }
      __syncthreads();
      sweep_half(As, p.wzr1, tile, 64, 32, 64, l, half, a);
      epi_zr_p(a, tile, half, l, p.bxz1, p.bxr1,
               p.z1 + (size_t)(t&1)*32768, p.r1 + (size_t)(t&1)*32768);
      setflag(p.fzr1 + (size_t)(wg-32)*32, (unsigned)(t+1));
    }
  } else if (wg < 80) {
    // ================= G0: g0 + h0-update(u) — 16 WGs =================
    const int gi = wg - 64;
    const int tile = gi*4 + (wid & 3);
    const int colB = (tile << 4) | (l & 15);
    const int r0 = half*16 + ((l >> 4) << 2);
    const float biasB = p.bxg0[colB];
    float hv[4] = {0.f,0.f,0.f,0.f};
    for (int u = 0; u < SS; ++u) {
      { uint4 Rx[4];
        issue_x(Rx, p.xb + (size_t)u*512, row, s16);
        commit4(Rx, As, 0, row, s16); }
      __syncthreads();
      f32x4 a = {0.f,0.f,0.f,0.f};
      sweep_half(As, p.wg0, tile, 48, 0, 16, l, half, a);
      // merged wait: fzr0>=u+1 | fg0>=u | fzr1>=u-3 | fg1>=u-3
      { const unsigned* f = nullptr; int need = 0;
        if (tid < 32)      { f = p.fzr0 + (size_t)tid*32;      need = u+1; }
        else if (tid < 48) { f = p.fg0  + (size_t)(tid-32)*32; need = u;   }
        else if (tid < 80) { f = p.fzr1 + (size_t)(tid-48)*32; need = u-3; }
        else if (tid < 96) { f = p.fg1  + (size_t)(tid-80)*32; need = u-3; }
        pollone(f, need);
        asm volatile("" ::: "memory");
        __syncthreads(); }
      { const float*    zr = p.z0 + (size_t)(u&1)*32768;
        const _Float16* rr = p.r0 + (size_t)(u&1)*32768;
        const _Float16* hh = p.h0h + (size_t)((u-1)&3)*32768;
        float zv[4];
        uint4 Ra[8], Rh[8];
        issue_prod(&Ra[0], &Rh[0], rr, hh, row, s16);
        issue_prod(&Ra[4], &Rh[4], rr+512, hh+512, row, s16);
        #pragma unroll
        for (int q = 0; q < 4; ++q)
          bload1(zv[q], zr + (size_t)(r0+q)*1024 + colB);
        asm volatile("s_waitcnt vmcnt(0)" ::: "memory");
        __builtin_amdgcn_sched_barrier(0);
        commit_prod(&Ra[0], &Rh[0], As, 1, row, s16);
        commit_prod(&Ra[4], &Rh[4], As, 2, row, s16);
        __syncthreads();
        sweep_half(As, p.wg0, tile, 48, 16, 48, l, half, a);
        float* hF = p.h0f + (size_t)(u&3)*32768;
        _Float16* hH = p.h0h + (size_t)(u&3)*32768;
        #pragma unroll
        for (int q = 0; q < 4; ++q) {
          const float g = tanhf(a[q] + biasB);
          const float hn = zv[q]*hv[q] + (1.f - zv[q])*g;
          hv[q] = hn;
          float o = __shfl_xor(hn, 1, 64);
          unsigned w = pkpair(hn);
          if (!(l & 1)) {
            astore2f(hF + (size_t)(r0+q)*1024 + colB, hn, o);
            astoreu((unsigned*)(hH + (size_t)(r0+q)*1024 + colB), w);
          }
        }
      }
      setflag(p.fg0 + (size_t)gi*32, (unsigned)(u+1));
    }
    #pragma unroll
    for (int q = 0; q < 4; ++q)
      p.out[OUT_HID_OFF + (size_t)(r0+q)*2048 + colB] = hv[q];
  } else if (wg < 96) {
    // ================= G1: g1 + h1-update(v) — 16 WGs =================
    const int gi = wg - 80;
    const int tile = gi*4 + (wid & 3);
    const int colB = (tile << 4) | (l & 15);
    const int r0 = half*16 + ((l >> 4) << 2);
    const float biasB = p.bxg1[colB];
    float hv[4] = {0.f,0.f,0.f,0.f};
    for (int v = 0; v < SS; ++v) {
      waitf(p.fg0, 16, v+1);                     // h0(v)
      { const _Float16* hb = p.h0h + (size_t)(v&3)*32768;
        uint4 R0[4], R1[4];
        issue_copy(R0, hb, row, s16);
        issue_copy(R1, hb+512, row, s16);
        asm volatile("s_waitcnt vmcnt(0)" ::: "memory");
        __builtin_amdgcn_sched_barrier(0);
        commit4(R0, As, 0, row, s16);
        commit4(R1, As, 1, row, s16); }
      __syncthreads();
      f32x4 a = {0.f,0.f,0.f,0.f};
      sweep_half(As, p.wg1, tile, 64, 0, 32, l, half, a);
      // merged wait: fzr1>=v+1 | fg1>=v | fy>=v-3
      { const unsigned* f = nullptr; int need = 0;
        if (tid < 32)      { f = p.fzr1 + (size_t)tid*32;      need = v+1; }
        else if (tid < 48) { f = p.fg1  + (size_t)(tid-32)*32; need = v;   }
        else if (tid < 52) { f = p.fy   + (size_t)(tid-48)*32; need = v-3; }
        pollone(f, need);
        asm volatile("" ::: "memory");
        __syncthreads(); }
      { const float*    zr = p.z1 + (size_t)(v&1)*32768;
        const _Float16* rr = p.r1 + (size_t)(v&1)*32768;
        const _Float16* hh = p.h1h + (size_t)((v-1)&3)*32768;
        float zv[4];
        uint4 Ra[8], Rh[8];
        issue_prod(&Ra[0], &Rh[0], rr, hh, row, s16);
        issue_prod(&Ra[4], &Rh[4], rr+512, hh+512, row, s16);
        #pragma unroll
        for (int q = 0; q < 4; ++q)
          bload1(zv[q], zr + (size_t)(r0+q)*1024 + colB);
        asm volatile("s_waitcnt vmcnt(0)" ::: "memory");
        __builtin_amdgcn_sched_barrier(0);
        commit_prod(&Ra[0], &Rh[0], As, 2, row, s16);
        commit_prod(&Ra[4], &Rh[4], As, 3, row, s16);
        __syncthreads();
        sweep_half(As, p.wg1, tile, 64, 32, 64, l, half, a);
        float* hF = p.h1f + (size_t)(v&3)*32768;
        _Float16* hH = p.h1h + (size_t)(v&3)*32768;
        #pragma unroll
        for (int q = 0; q < 4; ++q) {
          const float g = tanhf(a[q] + biasB);
          const float hn = zv[q]*hv[q] + (1.f - zv[q])*g;
          hv[q] = hn;
          float o = __shfl_xor(hn, 1, 64);
          unsigned w = pkpair(hn);
          if (!(l & 1)) {
            astore2f(hF + (size_t)(r0+q)*1024 + colB, hn, o);
            astoreu((unsigned*)(hH + (size_t)(r0+q)*1024 + colB), w);
          }
        }
      }
      setflag(p.fg1 + (size_t)gi*32, (unsigned)(v+1));
    }
    #pragma unroll
    for (int q = 0; q < 4; ++q)
      p.out[OUT_HID_OFF + (size_t)(r0+q)*2048 + 1024 + colB] = hv[q];
  } else {
    // ================= Y: y(w) — 4 WGs (r10 verbatim) =================
    const int ntg = (wg-96)*8 + wid;
    const int col = (ntg << 4) | (l & 15);
    const int brow = (l >> 4) << 2;
    const float bias = p.bhy[col];
    for (int w = 0; w < SS; ++w) {
      waitf(p.fg1, 16, w+1);                     // h1(w)
      { const _Float16* hb = p.h1h + (size_t)(w&3)*32768;
        uint4 R0[4], R1[4];
        issue_copy(R0, hb, row, s16);
        issue_copy(R1, hb+512, row, s16);
        asm volatile("s_waitcnt vmcnt(0)" ::: "memory");
        __builtin_amdgcn_sched_barrier(0);
        commit4(R0, As, 0, row, s16);
        commit4(R1, As, 1, row, s16); }
      __syncthreads();
      f32x4 a0 = {0.f,0.f,0.f,0.f}, a1 = {0.f,0.f,0.f,0.f};
      sweep_range(As, p.wy, ntg, 32, 0, 32, l, a0, a1);
      #pragma unroll
      for (int q = 0; q < 4; ++q) {
        p.out[(size_t)(brow+q)*262144    + (size_t)w*512 + col] = a0[q] + bias;
        p.out[(size_t)(brow+q+16)*262144 + (size_t)w*512 + col] = a1[q] + bias;
      }
      setflag(p.fy + (size_t)(wg-96)*32, (unsigned)(w+1));
    }
  }
}

// ---------- host ----------
extern "C" void kernel_launch(void* const* d_in, const int* in_sizes, int n_in,
                              void* d_out, int out_size, void* d_ws, size_t ws_size,
                              hipStream_t stream) {
  GP P;
  P.x    = (const float*)d_in[0];
  P.Wxz0 = (const float*)d_in[1];  P.bxz0 = (const float*)d_in[2];  P.Whz0 = (const float*)d_in[3];
  P.Wxr0 = (const float*)d_in[4];  P.bxr0 = (const float*)d_in[5];  P.Whr0 = (const float*)d_in[6];
  P.Wxg0 = (const float*)d_in[7];  P.bxg0 = (const float*)d_in[8];  P.Whg0 = (const float*)d_in[9];
  P.Wxz1 = (const float*)d_in[10]; P.bxz1 = (const float*)d_in[11]; P.Whz1 = (const float*)d_in[12];
  P.Wxr1 = (const float*)d_in[13]; P.bxr1 = (const float*)d_in[14]; P.Whr1 = (const float*)d_in[15];
  P.Wxg1 = (const float*)d_in[16]; P.bxg1 = (const float*)d_in[17]; P.Whg1 = (const float*)d_in[18];
  P.Why  = (const float*)d_in[19]; P.bhy  = (const float*)d_in[20];
  P.out  = (float*)d_out;

  char* ws = (char*)d_ws;
  P.xb   = (_Float16*)(ws + 0);           // 16777216
  P.wzr0 = (_Float16*)(ws + 16777216);    // 6291456
  P.wzr1 = (_Float16*)(ws + 23068672);    // 8388608
  P.wg0  = (_Float16*)(ws + 31457280);    // 3145728
  P.wg1  = (_Float16*)(ws + 34603008);    // 4194304
  P.wy   = (_Float16*)(ws + 38797312);    // 1048576
  P.h0f  = (float*)   (ws + 39845888);    // 524288  (4-ring f32)
  P.h1f  = (float*)   (ws + 40370176);    // 524288
  P.h0h  = (_Float16*)(ws + 40894464);    // 262144  (4-ring f16)
  P.h1h  = (_Float16*)(ws + 41156608);    // 262144
  P.z0   = (float*)   (ws + 41418752);    // 262144  (2-ring f32)
  P.z1   = (float*)   (ws + 41680896);    // 262144
  P.r0   = (_Float16*)(ws + 41943040);    // 131072  (2-ring f16)
  P.r1   = (_Float16*)(ws + 42074112);    // 131072
  P.fg0  = (unsigned*)(ws + 42205184);    // 2048
  P.fg1  = (unsigned*)(ws + 42207232);    // 2048
  P.fzr0 = (unsigned*)(ws + 42209280);    // 4096
  P.fzr1 = (unsigned*)(ws + 42213376);    // 4096
  P.fy   = (unsigned*)(ws + 42217472);    // 512

  // zero all rings + flags
  hipMemsetAsync(ws + 39845888, 0, 42217984 - 39845888, stream);

  pack<<<dim3(9728), dim3(256), 0, stream>>>(P);

  void* args[] = { &P };
  hipError_t err = hipLaunchCooperativeKernel((const void*)gru_main,
                                              dim3(NWG), dim3(NTHR), args, 0, stream);
  if (err != hipSuccess) {
    (void)hipGetLastError();   // clear sticky error, fall back to plain launch
    gru_main<<<dim3(NWG), dim3(NTHR), 0, stream>>>(P);
  }
}